// Round 8
// baseline (48.227 us; speedup 1.0000x reference)
//
#include <hip/hip_runtime.h>

// NeighborList: N=4096, cutoff 5.0, all pairs i<j (P = N(N-1)/2 = 8,386,560).
// Output (floats): [0,P) pair_i | [P,2P) pair_j | [2P,5P) diff[P,3] | [5P,6P) dist | [6P] n_pairs
//
// R7 = R6's proven store structure (4 pairs/thread wave-contiguous f4 stores,
// plain write-back — R3: nontemporal = 3x loss; R5: agent-scope release = L2
// drain disaster) + two changes:
//  (a) block processes 4 CONSECUTIVE 1024-pair groups (one sqrtf inversion +
//      cheap marching instead of 4 inversions),
//  (b) fused n_pairs via 2-level packed u64 atomics: each block does ONE
//      device-scope atomicAdd(count | 1<<32) into slot (bid&63); the 32nd
//      arriver owns the slot total (from the RETURN value -- pure RMW
//      dataflow, no fences/visibility assumptions) and forwards it to a main
//      slot; the 64th main arriver writes out[6P]. Max same-address
//      contention = 32 (R1: same-address storms serialize). Init by 520 B
//      hipMemsetAsync (R4: ticket start must be known).

typedef float f4 __attribute__((ext_vector_type(4)));

__global__ void zero_ws(int* __restrict__ ws, int n) {
    int t = blockIdx.x * blockDim.x + threadIdx.x;
    if (t < n) ws[t] = 0;
}

__global__ __launch_bounds__(256) void nl_kernel(const float* __restrict__ xyz,
                                                 float* __restrict__ out,
                                                 unsigned long long* __restrict__ wsll,
                                                 int* __restrict__ ws32,
                                                 int N, int P, int q, int slots) {
    const int tid = (int)threadIdx.x;
    int p0 = (int)blockIdx.x * 4096 + tid * 4;
    int cnt = 0;

    // one inversion per thread: rowstart(i) = i*(2N-1-i)/2 <= p0.
    // Radicand is exact in fp32 range (<2^27); sqrtf lands within +-2 and the
    // integer fixups make it exact.
    const int twoNm1 = 2 * N - 1;
    {
        const long long rad = (long long)twoNm1 * twoNm1 - 8LL * (long long)p0;
        const float s = sqrtf((float)rad);
        int ii = (int)(((float)twoNm1 - s) * 0.5f);
        if (ii > N - 2) ii = N - 2;
        if (ii < 0) ii = 0;
        int rs = ii * (2 * N - 1 - ii) / 2;
        while (p0 < rs) { --ii; rs -= (N - 1 - ii); }
        int next = rs + (N - 1 - ii);
        while (p0 >= next && ii < N - 2) { ++ii; rs = next; next += (N - 1 - ii); }

        #pragma unroll
        for (int g = 0; g < 4; ++g, p0 += 1024) {
            if (p0 >= P) break;
            // march row state to this group's start
            while (p0 >= next && ii < N - 2) { ++ii; rs = next; next += (N - 1 - ii); }

            float iv[4], jv[4], dxs[4], dys[4], dzs[4], dv[4];
            #pragma unroll
            for (int e = 0; e < 4; ++e) {
                const int p = p0 + e;
                while (p >= next && ii < N - 2) { ++ii; rs = next; next += (N - 1 - ii); }
                const int j = ii + 1 + (p - rs);
                float dx = 0.f, dy = 0.f, dz = 0.f, dist = 0.f, fi = -1.f, fj = -1.f;
                if (p < P) {
                    const float ax = xyz[3 * ii], ay = xyz[3 * ii + 1], az = xyz[3 * ii + 2];
                    const float bx = xyz[3 * j],  by = xyz[3 * j + 1],  bz = xyz[3 * j + 2];
                    const float tx = ax - bx, ty = ay - by, tz = az - bz;
                    const float d = sqrtf(tx * tx + ty * ty + tz * tz);
                    if (d < 5.0f) {              // mirror reference: sqrt then compare
                        fi = (float)ii; fj = (float)j;
                        dx = tx; dy = ty; dz = tz; dist = d;
                        ++cnt;
                    }
                }
                iv[e] = fi; jv[e] = fj; dxs[e] = dx; dys[e] = dy; dzs[e] = dz; dv[e] = dist;
            }

            if (p0 + 4 <= P) {   // p0 mult of 4 -> 16B-aligned, wave-contiguous
                *(f4*)(out + p0)     = (f4){iv[0], iv[1], iv[2], iv[3]};
                *(f4*)(out + P + p0) = (f4){jv[0], jv[1], jv[2], jv[3]};
                f4* dp = (f4*)(out + 2 * P + 3 * p0);
                dp[0] = (f4){dxs[0], dys[0], dzs[0], dxs[1]};
                dp[1] = (f4){dys[1], dzs[1], dxs[2], dys[2]};
                dp[2] = (f4){dzs[2], dxs[3], dys[3], dzs[3]};
                *(f4*)(out + 5 * P + p0) = (f4){dv[0], dv[1], dv[2], dv[3]};
            } else {
                for (int e = 0; e < 4 && p0 + e < P; ++e) {
                    const int p = p0 + e;
                    out[p] = iv[e]; out[P + p] = jv[e];
                    out[2 * P + 3 * p]     = dxs[e];
                    out[2 * P + 3 * p + 1] = dys[e];
                    out[2 * P + 3 * p + 2] = dzs[e];
                    out[5 * P + p] = dv[e];
                }
            }
        }
    }

    // block count reduce
    for (int o = 32; o > 0; o >>= 1) cnt += __shfl_down(cnt, o, 64);
    __shared__ int sh[4];
    if ((tid & 63) == 0) sh[tid >> 6] = cnt;
    __syncthreads();
    if (tid == 0) {
        const unsigned int c = (unsigned int)(sh[0] + sh[1] + sh[2] + sh[3]);
        if (q > 0) {
            // fused path: packed {arrivals:32 | count:32} u64 RMW dataflow
            unsigned long long old =
                atomicAdd(&wsll[blockIdx.x & 63], (unsigned long long)c + (1ull << 32));
            if ((old >> 32) == (unsigned long long)(q - 1)) {
                const unsigned long long slot_total = (old & 0xffffffffull) + c;
                unsigned long long old2 =
                    atomicAdd(&wsll[64], slot_total + (1ull << 32));
                if ((old2 >> 32) == 63ull)
                    out[6 * P] = (float)((old2 & 0xffffffffull) + slot_total);
            }
        } else {
            if ((int)gridDim.x <= slots) ws32[blockIdx.x] = (int)c;
            else if (c) atomicAdd(&ws32[blockIdx.x % slots], (int)c);
        }
    }
}

__global__ void finalize_kernel(float* __restrict__ out, const int* __restrict__ ws,
                                int n, int pos) {
    const int t = threadIdx.x;  // 256
    int s = 0;
    for (int k = t; k < n; k += 256) s += ws[k];
    for (int o = 32; o > 0; o >>= 1) s += __shfl_down(s, o, 64);
    __shared__ int sh[4];
    if ((t & 63) == 0) sh[t >> 6] = s;
    __syncthreads();
    if (t == 0) out[pos] = (float)(sh[0] + sh[1] + sh[2] + sh[3]);
}

extern "C" void kernel_launch(void* const* d_in, const int* in_sizes, int n_in,
                              void* d_out, int out_size, void* d_ws, size_t ws_size,
                              hipStream_t stream) {
    const float* xyz = (const float*)d_in[0];
    float* out = (float*)d_out;

    const int N = in_sizes[0] / 3;                          // 4096
    const int P = (int)((long long)N * (N - 1) / 2);        // 8,386,560
    const int nb = (P + 4095) / 4096;                       // 2048 for N=4096

    if ((nb & 63) == 0 && ws_size >= 65 * sizeof(unsigned long long)) {
        // fused: wsll[0..63] packed slot accumulators, wsll[64] main
        hipMemsetAsync(d_ws, 0, 65 * sizeof(unsigned long long), stream);
        nl_kernel<<<nb, 256, 0, stream>>>(xyz, out, (unsigned long long*)d_ws,
                                          (int*)d_ws, N, P, nb >> 6, 0);
    } else {
        int* ws32 = (int*)d_ws;
        const int cap = (int)(ws_size / 4);
        const int slots = (nb <= cap) ? nb : (cap < 1 ? 1 : cap);
        if (nb > slots) zero_ws<<<(slots + 255) / 256, 256, 0, stream>>>(ws32, slots);
        nl_kernel<<<nb, 256, 0, stream>>>(xyz, out, (unsigned long long*)d_ws,
                                          ws32, N, P, 0, slots);
        finalize_kernel<<<1, 256, 0, stream>>>(out, ws32, slots, 6 * P);
    }
}